// Round 3
// baseline (795.417 us; speedup 1.0000x reference)
//
#include <hip/hip_runtime.h>
#include <cstdint>
#include <math.h>

// Problem constants
#define NMC   16
#define SDIM  4
#define ODIM  3
#define TLEN  128
#define BDIM  256
#define MDIM  32
#define HLDIM 64
#define PARD  36

#define LOG2PI_F 1.8378770664093453f

// ---------------------------------------------------------------------------
// threefry2x32 (JAX-compatible, 20 rounds)
// ---------------------------------------------------------------------------
__host__ __device__ inline void threefry2x32(uint32_t k0, uint32_t k1,
                                             uint32_t x0, uint32_t x1,
                                             uint32_t* o0, uint32_t* o1) {
  uint32_t ks0 = k0, ks1 = k1, ks2 = k0 ^ k1 ^ 0x1BD11BDAu;
  x0 += ks0; x1 += ks1;
#define TF_R(r) { x0 += x1; x1 = (x1 << (r)) | (x1 >> (32 - (r))); x1 ^= x0; }
  TF_R(13) TF_R(15) TF_R(26) TF_R(6)  x0 += ks1; x1 += ks2 + 1u;
  TF_R(17) TF_R(29) TF_R(16) TF_R(24) x0 += ks2; x1 += ks0 + 2u;
  TF_R(13) TF_R(15) TF_R(26) TF_R(6)  x0 += ks0; x1 += ks1 + 3u;
  TF_R(17) TF_R(29) TF_R(16) TF_R(24) x0 += ks1; x1 += ks2 + 4u;
  TF_R(13) TF_R(15) TF_R(26) TF_R(6)  x0 += ks2; x1 += ks0 + 5u;
#undef TF_R
  *o0 = x0; *o1 = x1;
}

// XLA f32 ErfInv polynomial
__device__ inline float erfinv_f32(float x) {
  float w = -log1pf(-x * x);
  float p;
  if (w < 5.0f) {
    w -= 2.5f;
    p = 2.81022636e-08f;
    p = fmaf(p, w, 3.43273939e-07f);
    p = fmaf(p, w, -3.5233877e-06f);
    p = fmaf(p, w, -4.39150654e-06f);
    p = fmaf(p, w, 0.00021858087f);
    p = fmaf(p, w, -0.00125372503f);
    p = fmaf(p, w, -0.00417768164f);
    p = fmaf(p, w, 0.246640727f);
    p = fmaf(p, w, 1.50140941f);
  } else {
    w = sqrtf(w) - 3.0f;
    p = -0.000200214257f;
    p = fmaf(p, w, 0.000100950558f);
    p = fmaf(p, w, 0.00134934322f);
    p = fmaf(p, w, -0.00367342844f);
    p = fmaf(p, w, 0.00573950773f);
    p = fmaf(p, w, -0.0076224613f);
    p = fmaf(p, w, 0.00943887047f);
    p = fmaf(p, w, 1.00167406f);
    p = fmaf(p, w, 2.83297682f);
  }
  return p * x;
}

__device__ inline float bits_to_normal(uint32_t b) {
  float f = __uint_as_float((b >> 9) | 0x3F800000u) - 1.0f;  // [0,1)
  const float lo = -0.99999994f;
  float u = f * 2.0f + lo;
  u = fmaxf(lo, u);
  return 1.41421356f * erfinv_f32(u);
}

// ---------------------------------------------------------------------------
// DPP-based allreduce over 32 lanes
// ---------------------------------------------------------------------------
#define DPP_ROR_ADD(v, ctrl) \
  ((v) + __int_as_float(__builtin_amdgcn_update_dpp(0, __float_as_int(v), (ctrl), 0xf, 0xf, false)))

__device__ __forceinline__ float allred32(float v) {
  v = DPP_ROR_ADD(v, 0x128);  // row_ror:8
  v = DPP_ROR_ADD(v, 0x124);  // row_ror:4
  v = DPP_ROR_ADD(v, 0x122);  // row_ror:2
  v = DPP_ROR_ADD(v, 0x121);  // row_ror:1
  return v + __shfl_xor(v, 16);
}

__device__ __forceinline__ float sigm_fast(float x) {
  return 1.0f / (1.0f + __expf(-x));
}
__device__ __forceinline__ float tanh_fast(float x) {
  return 1.0f - 2.0f / (1.0f + __expf(2.0f * x));
}

// ===========================================================================
// PREP parts (fused kernel; 256 threads; shared smem arena 12480 floats)
// ===========================================================================

// ---- MLP part: blocks [0,512), 64 rows/block -------------------------------
#define MLP_SB 128
__device__ void mlp_part(
    float* smem, const float* __restrict__ obs,
    const float* __restrict__ W1, const float* __restrict__ b1,
    const float* __restrict__ W2, const float* __restrict__ b2,
    const float* __restrict__ W3, const float* __restrict__ b3,
    const float* __restrict__ W4, const float* __restrict__ b4,
    float* __restrict__ par_g) {
  float* xs  = smem;           // [3][64]
  float* A_l = smem + 192;     // 64*64
  float* B_l = smem + 192 + 4096;  // 64*128
  const int tid = threadIdx.x;
  const int R0 = blockIdx.x * 64;
  const int tr = tid & 15;
  const int tj = tid >> 4;

  for (int idx = tid; idx < 192; idx += 256) {
    int r = idx & 63, o = idx >> 6;
    xs[o * 64 + r] = obs[(R0 + r) * 3 + o];
  }

  float acc2[4][8];
#pragma unroll
  for (int i = 0; i < 4; ++i)
#pragma unroll
    for (int j = 0; j < 8; ++j) acc2[i][j] = 0.f;

  for (int kc = 0; kc < 4; ++kc) {
    __syncthreads();
    {  // stage W2 chunk transposed
      int j = tid & 127, kh = (tid >> 7) * 32;
      const float4* wsrc = (const float4*)(W2 + j * 256 + kc * 64 + kh);
#pragma unroll
      for (int q = 0; q < 8; ++q) {
        float4 v = wsrc[q];
        int k = kh + q * 4;
        B_l[(k + 0) * MLP_SB + j] = v.x;
        B_l[(k + 1) * MLP_SB + j] = v.y;
        B_l[(k + 2) * MLP_SB + j] = v.z;
        B_l[(k + 3) * MLP_SB + j] = v.w;
      }
    }
    {  // layer1 on the fly
      int r = tid & 63, q4 = tid >> 6;
      float x0 = xs[r], x1 = xs[64 + r], x2 = xs[128 + r];
      const float4* w1p = (const float4*)(W1 + (kc * 64 + q4 * 16) * 3);
      float4 wv[12];
#pragma unroll
      for (int q = 0; q < 12; ++q) wv[q] = w1p[q];
      const float* wf = (const float*)wv;
#pragma unroll
      for (int i = 0; i < 16; ++i) {
        int k = q4 * 16 + i;
        float v = b1[kc * 64 + k] + wf[i * 3] * x0 + wf[i * 3 + 1] * x1 + wf[i * 3 + 2] * x2;
        A_l[k * 64 + r] = fmaxf(v, 0.f);
      }
    }
    __syncthreads();
    for (int k = 0; k < 64; ++k) {
      float4 av = *(const float4*)&A_l[k * 64 + tr * 4];
      float4 b0 = *(const float4*)&B_l[k * MLP_SB + tj * 8];
      float4 b1v = *(const float4*)&B_l[k * MLP_SB + tj * 8 + 4];
      const float a4[4] = {av.x, av.y, av.z, av.w};
      const float bv8[8] = {b0.x, b0.y, b0.z, b0.w, b1v.x, b1v.y, b1v.z, b1v.w};
#pragma unroll
      for (int ri = 0; ri < 4; ++ri)
#pragma unroll
        for (int ji = 0; ji < 8; ++ji)
          acc2[ri][ji] = fmaf(a4[ri], bv8[ji], acc2[ri][ji]);
    }
  }
  __syncthreads();
#pragma unroll
  for (int ji = 0; ji < 8; ++ji) {
    int j = tj * 8 + ji;
    float bias = b2[j];
    float4 hv;
    hv.x = fmaxf(acc2[0][ji] + bias, 0.f);
    hv.y = fmaxf(acc2[1][ji] + bias, 0.f);
    hv.z = fmaxf(acc2[2][ji] + bias, 0.f);
    hv.w = fmaxf(acc2[3][ji] + bias, 0.f);
    *(float4*)&B_l[j * 64 + tr * 4] = hv;
  }

  float acc3[4][4];
#pragma unroll
  for (int i = 0; i < 4; ++i)
#pragma unroll
    for (int j = 0; j < 4; ++j) acc3[i][j] = 0.f;

  for (int kc = 0; kc < 2; ++kc) {
    __syncthreads();
    {
      int j = tid & 63, kq = (tid >> 6) * 16;
      const float4* wsrc = (const float4*)(W3 + j * 128 + kc * 64 + kq);
#pragma unroll
      for (int q = 0; q < 4; ++q) {
        float4 v = wsrc[q];
        int k = kq + q * 4;
        A_l[(k + 0) * 64 + j] = v.x;
        A_l[(k + 1) * 64 + j] = v.y;
        A_l[(k + 2) * 64 + j] = v.z;
        A_l[(k + 3) * 64 + j] = v.w;
      }
    }
    __syncthreads();
    for (int k = 0; k < 64; ++k) {
      float4 av = *(const float4*)&B_l[(kc * 64 + k) * 64 + tr * 4];
      float4 bv = *(const float4*)&A_l[k * 64 + (tj & 15) * 4];
      const float a4[4] = {av.x, av.y, av.z, av.w};
      const float b4v[4] = {bv.x, bv.y, bv.z, bv.w};
#pragma unroll
      for (int ri = 0; ri < 4; ++ri)
#pragma unroll
        for (int ji = 0; ji < 4; ++ji)
          acc3[ri][ji] = fmaf(a4[ri], b4v[ji], acc3[ri][ji]);
    }
  }
  __syncthreads();
#pragma unroll
  for (int ji = 0; ji < 4; ++ji) {
    int j = tj * 4 + ji;
    float bias = b3[j];
    float4 hv;
    hv.x = fmaxf(acc3[0][ji] + bias, 0.f);
    hv.y = fmaxf(acc3[1][ji] + bias, 0.f);
    hv.z = fmaxf(acc3[2][ji] + bias, 0.f);
    hv.w = fmaxf(acc3[3][ji] + bias, 0.f);
    *(float4*)&A_l[j * 64 + tr * 4] = hv;
  }
  __syncthreads();

  {
    int r = tid & 63;
    int jg = __builtin_amdgcn_readfirstlane(tid >> 6);
    float accp[9];
#pragma unroll
    for (int i = 0; i < 9; ++i) accp[i] = b4[jg * 9 + i];
    for (int k = 0; k < 64; ++k) {
      float hv = A_l[k * 64 + r];
#pragma unroll
      for (int i = 0; i < 9; ++i)
        accp[i] = fmaf(hv, W4[(jg * 9 + i) * 64 + k], accp[i]);
    }
#pragma unroll
    for (int i = 0; i < 9; ++i) par_g[(R0 + r) * 36 + jg * 9 + i] = accp[i];
  }
}

// ---- LSTM part: blocks [512,768) -------------------------------------------
__device__ void lstm_part(
    float* smem, int b, const float* __restrict__ obs,
    const float* __restrict__ Wih, const float* __restrict__ Whh,
    const float* __restrict__ b_lstm,
    const float* __restrict__ Wm, const float* __restrict__ bm,
    const float* __restrict__ Wv, const float* __restrict__ bv,
    float* __restrict__ m0_g, float* __restrict__ v0_g, float* __restrict__ acc) {
  float* g_l = smem;          // [2][4][64]
  float* h_w = smem + 512;    // [4][64]
  float* mv_l = smem + 768;   // 8
  float* obl = smem + 776;    // [128][4] padded, 16B-aligned (776*4=3104)
  const int tid = threadIdx.x;
  const int w = tid >> 6;
  const int l = tid & 63;

  for (int i = tid; i < 384; i += 256) obl[(i / 3) * 4 + (i % 3)] = obs[b * 384 + i];

  float whh_r[64];
  {
    const float4* wsrc = (const float4*)(Whh + tid * 64);
#pragma unroll
    for (int q = 0; q < 16; ++q) {
      float4 v = wsrc[q];
      whh_r[q * 4 + 0] = v.x; whh_r[q * 4 + 1] = v.y;
      whh_r[q * 4 + 2] = v.z; whh_r[q * 4 + 3] = v.w;
    }
  }
  const float wih0 = Wih[tid * 3 + 0];
  const float wih1 = Wih[tid * 3 + 1];
  const float wih2 = Wih[tid * 3 + 2];
  const float bb = b_lstm[tid];

  float c_ = 0.0f;
  h_w[w * 64 + l] = 0.0f;
  __syncthreads();

#pragma unroll 1
  for (int t = 0; t < TLEN; ++t) {
    const float4 xv = *(const float4*)&obl[t * 4];
    const float4* h4 = (const float4*)&h_w[w * 64];
    float a0 = 0.f, a1 = 0.f, a2 = 0.f, a3 = 0.f;
#pragma unroll
    for (int q = 0; q < 16; ++q) {
      float4 hv = h4[q];
      a0 = fmaf(whh_r[q * 4 + 0], hv.x, a0);
      a1 = fmaf(whh_r[q * 4 + 1], hv.y, a1);
      a2 = fmaf(whh_r[q * 4 + 2], hv.z, a2);
      a3 = fmaf(whh_r[q * 4 + 3], hv.w, a3);
    }
    float g = fmaf(wih0, xv.x, fmaf(wih1, xv.y, fmaf(wih2, xv.z, bb))) + ((a0 + a1) + (a2 + a3));
    g_l[((t & 1) * 4 + w) * 64 + l] = g;
    __syncthreads();
    float gi = g_l[((t & 1) * 4 + 0) * 64 + l];
    float gf = g_l[((t & 1) * 4 + 1) * 64 + l];
    float gg = g_l[((t & 1) * 4 + 2) * 64 + l];
    float go = g_l[((t & 1) * 4 + 3) * 64 + l];
    c_ = sigm_fast(gf) * c_ + sigm_fast(gi) * tanh_fast(gg);
    h_w[w * 64 + l] = sigm_fast(go) * tanh_fast(c_);
  }

  if (tid < 8) {
    const int s = tid & 3;
    const bool isv = tid >= 4;
    const float* W = isv ? (Wv + s * 64) : (Wm + s * 64);
    float a = isv ? bv[s] : bm[s];
#pragma unroll
    for (int k = 0; k < 64; ++k) a += W[k] * h_w[k];
    if (!isv) {
      m0_g[b * 4 + s] = a;
      mv_l[s] = a;
    } else {
      float sp = (a > 0.f) ? (a + log1pf(expf(-a))) : log1pf(expf(a));
      float v = sp + 1e-6f;
      v0_g[b * 4 + s] = v;
      mv_l[4 + s] = v;
    }
  }
  if (tid == 0) {
    float s = 0.f;
#pragma unroll
    for (int k = 0; k < 4; ++k) {
      float m = mv_l[k], v = mv_l[4 + k];
      s += 0.5f * (v + m * m - 1.0f - logf(v));
    }
    atomicAdd(&acc[0], s);
  }
}

// ---- SETUP part: blocks [768,772), per-d -----------------------------------
__device__ void setup_part(
    float* smem, int d, const float* __restrict__ Z,
    const float* __restrict__ log_ls, const float* __restrict__ log_os,
    const float* __restrict__ m_u, const float* __restrict__ L_u,
    uint32_t kUa, uint32_t kUb,
    float* __restrict__ Kinv_g, float* __restrict__ alpha_g, float* __restrict__ acc) {
  float* Kl    = smem;          // 32*33
  float* work  = smem + 1056;   // 32*33
  float* Ul    = smem + 2112;   // 16*32
  float* red   = smem + 2624;   // 64
  float* epsUl = smem + 2688;   // 16*32
  const int tid = threadIdx.x;

  // epsU generation (counter pairs (j, j+1024) map to nn and nn+8, same d)
  {
    int nn7 = tid >> 5, k = tid & 31;  // tid < 256 -> nn7 < 8
    uint32_t j = (uint32_t)((nn7 * 4 + d) * 32 + k);
    uint32_t o0, o1;
    threefry2x32(kUa, kUb, j, j + 1024u, &o0, &o1);
    epsUl[nn7 * 32 + k] = bits_to_normal(o0);
    epsUl[(nn7 + 8) * 32 + k] = bits_to_normal(o1);
  }

  float il[4];
#pragma unroll
  for (int k = 0; k < 4; ++k) il[k] = expf(-log_ls[d * 4 + k]);
  const float osd = expf(log_os[d]);

  for (int e = tid; e < 1024; e += 256) {
    int i = e >> 5, j = e & 31;
    float s = 0.f;
#pragma unroll
    for (int k = 0; k < 4; ++k) {
      float t_ = (Z[d * 128 + i * 4 + k] - Z[d * 128 + j * 4 + k]) * il[k];
      s += t_ * t_;
    }
    float v = osd * expf(-0.5f * s);
    if (i == j) v += 1e-5f;
    Kl[i * 33 + j] = v;
  }
  __syncthreads();

  // Cholesky (lower), in place
  for (int jc = 0; jc < 32; ++jc) {
    if (tid == jc) {
      float s = Kl[jc * 33 + jc];
      for (int p = 0; p < jc; ++p) s -= Kl[jc * 33 + p] * Kl[jc * 33 + p];
      Kl[jc * 33 + jc] = sqrtf(s);
    }
    __syncthreads();
    if (tid > jc && tid < 32) {
      float s = Kl[tid * 33 + jc];
      for (int p = 0; p < jc; ++p) s -= Kl[tid * 33 + p] * Kl[jc * 33 + p];
      Kl[tid * 33 + jc] = s / Kl[jc * 33 + jc];
    }
    __syncthreads();
  }

  // Kinv column per thread, register-resident, fully unrolled
  if (tid < 32) {
    const int col = tid;
    float rdiag[32];
#pragma unroll
    for (int r = 0; r < 32; ++r) rdiag[r] = __builtin_amdgcn_rcpf(Kl[r * 33 + r]);
    float w[32];
#pragma unroll
    for (int r = 0; r < 32; ++r) {
      float s = (r == col) ? 1.f : 0.f;
#pragma unroll
      for (int p = 0; p < 32; ++p)
        if (p < r) s -= Kl[r * 33 + p] * w[p];  // zeros propagate for r<col
      w[r] = s * rdiag[r];
    }
    float w2[32];
#pragma unroll
    for (int rr = 0; rr < 32; ++rr) {
      const int r = 31 - rr;
      float s = w[r];
#pragma unroll
      for (int p = 0; p < 32; ++p)
        if (p > r) s -= Kl[p * 33 + r] * w2[p];
      w2[r] = s * rdiag[r];
    }
#pragma unroll
    for (int r = 0; r < 32; ++r) {
      Kinv_g[(d * 32 + r) * 32 + col] = w2[r];
      work[col * 33 + r] = w2[r];
    }
  }
  // Ul = m_u + tril(L_u) @ epsU
  for (int e = tid; e < 512; e += 256) {
    int nn = e >> 5, m = e & 31;
    float s = m_u[d * 32 + m];
    for (int k = 0; k <= m; ++k)
      s += L_u[(d * 32 + m) * 32 + k] * epsUl[nn * 32 + k];
    Ul[nn * 32 + m] = s;
  }
  __syncthreads();
  // alpha = Kinv @ U
  for (int e = tid; e < 512; e += 256) {
    int nn = e >> 5, m = e & 31;
    float s = 0.f;
    for (int mm = 0; mm < 32; ++mm) s += work[mm * 33 + m] * Ul[nn * 32 + mm];
    alpha_g[(d * 16 + nn) * 32 + m] = s;
  }

  // gpKL: A = L^{-1} tril(L_u) col-per-thread (registers); bq on lane 32
  float contrib = 0.f;
  if (tid < 32) {
    const int col = tid;
    float rdiag[32];
#pragma unroll
    for (int r = 0; r < 32; ++r) rdiag[r] = __builtin_amdgcn_rcpf(Kl[r * 33 + r]);
    float v[32];
    float sa = 0.f;
#pragma unroll
    for (int r = 0; r < 32; ++r) {
      float lu = L_u[(d * 32 + r) * 32 + col];
      float s = (col <= r) ? lu : 0.f;
#pragma unroll
      for (int p = 0; p < 32; ++p)
        if (p < r) s -= Kl[r * 33 + p] * v[p];
      float vv = s * rdiag[r];
      v[r] = vv;
      sa += vv * vv;
    }
    contrib = sa;
  } else if (tid < 64) {
    float bq[32];
    float sb = 0.f;
#pragma unroll
    for (int r = 0; r < 32; ++r) {
      float s = m_u[d * 32 + r];
#pragma unroll
      for (int p = 0; p < 32; ++p)
        if (p < r) s -= Kl[r * 33 + p] * bq[p];
      float vv = s * __builtin_amdgcn_rcpf(Kl[r * 33 + r]);
      bq[r] = vv;
      sb += vv * vv;
    }
    contrib = (tid == 32) ? sb : 0.f;
  }
  if (tid < 64) red[tid] = contrib;
  __syncthreads();
  if (tid == 0) {
    float s = 0.f;
    for (int i = 0; i < 64; ++i) s += red[i];
    float ldK = 0.f, ldS = 0.f;
    for (int r = 0; r < 32; ++r) {
      ldK += logf(Kl[r * 33 + r]);
      ldS += logf(fabsf(L_u[(d * 32 + r) * 32 + r]) + 1e-12f);
    }
    float g = s - 32.0f + 2.0f * ldK - 2.0f * ldS;
    atomicAdd(&acc[1], 0.5f * g / (128.0f * 256.0f));
  }
}

// ---- Fused prep kernel -----------------------------------------------------
__global__ __launch_bounds__(256) void prep_kernel(
    const float* obs,
    const float* W1, const float* b1, const float* W2, const float* b2,
    const float* W3, const float* b3, const float* W4, const float* b4,
    const float* Wih, const float* Whh, const float* b_lstm,
    const float* Wm, const float* bm, const float* Wv, const float* bv,
    const float* Z, const float* log_ls, const float* log_os,
    const float* m_u, const float* L_u,
    uint32_t kUa, uint32_t kUb, uint32_t kqa, uint32_t kqb,
    float* par_g, float* m0_g, float* v0_g,
    float* Kinv_g, float* alpha_g, float* epsq, float* acc) {
  __shared__ __align__(16) float smem[12480];  // 49,920 B arena (union)
  const int bx = blockIdx.x;
  if (bx < 512) {
    mlp_part(smem, obs, W1, b1, W2, b2, W3, b3, W4, b4, par_g);
  } else if (bx < 768) {
    lstm_part(smem, bx - 512, obs, Wih, Whh, b_lstm, Wm, bm, Wv, bv, m0_g, v0_g, acc);
  } else if (bx < 772) {
    setup_part(smem, bx - 768, Z, log_ls, log_os, m_u, L_u, kUa, kUb,
               Kinv_g, alpha_g, acc);
  } else {
    uint32_t j = (uint32_t)(bx - 772) * 256u + (uint32_t)threadIdx.x;
    uint32_t o0, o1;
    threefry2x32(kqa, kqb, j, j + 1048576u, &o0, &o1);
    epsq[j] = bits_to_normal(o0);
    epsq[j + 1048576u] = bits_to_normal(o1);
  }
}

// ===========================================================================
// Scan: 4096 chains; 32 lanes/chain; LDS-staged par/obs; in-kernel eps0 RNG.
// ===========================================================================
__global__ __launch_bounds__(256, 2) void scan_kernel(
    const float* __restrict__ Z, const float* __restrict__ log_ls,
    const float* __restrict__ log_os, const float* __restrict__ noise_proc,
    const float* __restrict__ noise_emis, const float* __restrict__ obs,
    const float* __restrict__ par_g, const float* __restrict__ m0_g,
    const float* __restrict__ v0_g, const float* __restrict__ epsq,
    const float* __restrict__ Kinv_g, const float* __restrict__ alpha_g,
    uint32_t k0a, uint32_t k0b, float* __restrict__ acc) {
  __shared__ __align__(16) float parl[32 * 36];
  __shared__ __align__(16) float obsl[32 * 4];
  __shared__ __align__(16) float eps0l[8 * 4 * 4];
  __shared__ __align__(16) float kbuf[8 * 4 * 32];
  const int tid = threadIdx.x;
  const int c = tid >> 5;
  const int m = tid & 31;
  const int b = blockIdx.x >> 1;
  const int nb = (blockIdx.x & 1) << 3;
  const int n = nb + c;

  // eps0 RNG: pairs (j, j+32768) map to n and n+8 (same block half selects)
  if (tid < 128) {
    int cc = tid >> 4, dd = (tid >> 2) & 3, ss = tid & 3;
    uint32_t j = (uint32_t)((((cc * 4 + dd) * 256 + b) * 4) + ss);
    uint32_t o0, o1;
    threefry2x32(k0a, k0b, j, j + 32768u, &o0, &o1);
    eps0l[(cc * 4 + dd) * 4 + ss] = bits_to_normal(nb ? o1 : o0);
  }

  float zr[4][4], ilr[4][4], osr[4];
#pragma unroll
  for (int d = 0; d < 4; ++d) {
#pragma unroll
    for (int k = 0; k < 4; ++k) {
      zr[d][k] = Z[d * 128 + m * 4 + k];
      ilr[d][k] = expf(-log_ls[d * 4 + k]);
    }
    osr[d] = expf(log_os[d]);
  }
  float kinv[4][32];
  {
    const float4* kg4 = (const float4*)Kinv_g;
#pragma unroll
    for (int d = 0; d < 4; ++d) {
#pragma unroll
      for (int q = 0; q < 8; ++q) {
        float4 v = kg4[(d * 32 + m) * 8 + q];
        kinv[d][q * 4 + 0] = v.x;
        kinv[d][q * 4 + 1] = v.y;
        kinv[d][q * 4 + 2] = v.z;
        kinv[d][q * 4 + 3] = v.w;
      }
    }
  }
  float alr[4];
#pragma unroll
  for (int d = 0; d < 4; ++d) alr[d] = alpha_g[(d * 16 + n) * 32 + m];
  float np_[4];
#pragma unroll
  for (int k = 0; k < 4; ++k) np_[k] = noise_proc[k];
  const float ine0 = __builtin_amdgcn_rcpf(noise_emis[0]);
  const float ine1 = __builtin_amdgcn_rcpf(noise_emis[1]);
  const float ine2 = __builtin_amdgcn_rcpf(noise_emis[2]);
  const float cst = 3.0f * LOG2PI_F + logf(noise_emis[0]) + logf(noise_emis[1]) + logf(noise_emis[2]);

  const float4 m0v = *(const float4*)(m0_g + b * 4);
  const float4 v0v = *(const float4*)(v0_g + b * 4);
  const float sq0 = sqrtf(v0v.x), sq1 = sqrtf(v0v.y), sq2 = sqrtf(v0v.z), sq3 = sqrtf(v0v.w);

  const size_t evbase = (size_t)n * 256 + b;  // (t*16+n)*256+b scaled below

  float x0r = 0.f, x1r = 0.f, x2r = 0.f, x3r = 0.f;
  float kl_acc = 0.f, ell_acc = 0.f;

  for (int tc = 0; tc < 4; ++tc) {
    __syncthreads();
    {  // stage par chunk (32 steps x 36) and obs chunk
      const float4* src = (const float4*)(par_g + (size_t)b * 4608 + tc * 1152);
      float4* dst = (float4*)parl;
      for (int i = tid; i < 288; i += 256) dst[i] = src[i];
      if (tid < 96) obsl[(tid / 3) * 4 + (tid % 3)] = obs[b * 384 + tc * 96 + tid];
    }
    __syncthreads();

#pragma unroll 1
    for (int tt = 0; tt < 32; ++tt) {
      const int t = tc * 32 + tt;
      const float4* pv = (const float4*)&parl[tt * 36];
      const float4 a0 = pv[0], a1 = pv[1], a2 = pv[2], a3 = pv[3];
      const float4 btv = pv[4];
      const float4 s0 = pv[5], s1 = pv[6], s2 = pv[7], s3 = pv[8];
      const float4 ov = *(const float4*)&obsl[tt * 4];
      const float4 ev = *(const float4*)(epsq + (size_t)t * 16384 + evbase * 4);

      // phase 1: RBF features
      float kreg[4];
#pragma unroll
      for (int d = 0; d < 4; ++d) {
        float xt0, xt1, xt2, xt3;
        if (t == 0) {
          const float4 e0 = *(const float4*)&eps0l[(c * 4 + d) * 4];
          xt0 = fmaf(sq0, e0.x, m0v.x);
          xt1 = fmaf(sq1, e0.y, m0v.y);
          xt2 = fmaf(sq2, e0.z, m0v.z);
          xt3 = fmaf(sq3, e0.w, m0v.w);
        } else {
          xt0 = x0r; xt1 = x1r; xt2 = x2r; xt3 = x3r;
        }
        float d0_ = (xt0 - zr[d][0]) * ilr[d][0];
        float d1_ = (xt1 - zr[d][1]) * ilr[d][1];
        float d2_ = (xt2 - zr[d][2]) * ilr[d][2];
        float d3_ = (xt3 - zr[d][3]) * ilr[d][3];
        float ss = d0_ * d0_ + d1_ * d1_ + d2_ * d2_ + d3_ * d3_;
        float km = osr[d] * __expf(-0.5f * ss);
        kreg[d] = km;
        kbuf[(c * 4 + d) * 32 + m] = km;  // half-wave private
      }

      // phase 2: mean / quad form
      float gm[4], gv[4];
#pragma unroll
      for (int d = 0; d < 4; ++d) {
        const float4* kb4 = (const float4*)&kbuf[(c * 4 + d) * 32];
        float ya = 0.f, yb = 0.f, yc = 0.f, yd = 0.f;
#pragma unroll
        for (int q = 0; q < 8; ++q) {
          float4 kv = kb4[q];
          ya = fmaf(kinv[d][q * 4 + 0], kv.x, ya);
          yb = fmaf(kinv[d][q * 4 + 1], kv.y, yb);
          yc = fmaf(kinv[d][q * 4 + 2], kv.z, yc);
          yd = fmaf(kinv[d][q * 4 + 3], kv.w, yd);
        }
        float y = (ya + yb) + (yc + yd);
        gm[d] = allred32(kreg[d] * alr[d]);
        float qp = allred32(kreg[d] * y);
        gv[d] = fmaxf(osr[d] - qp, 1e-8f);
      }

      // tail
      float qm0 = btv.x + a0.x * gm[0] + a0.y * gm[1] + a0.z * gm[2] + a0.w * gm[3];
      float qm1 = btv.y + a1.x * gm[0] + a1.y * gm[1] + a1.z * gm[2] + a1.w * gm[3];
      float qm2 = btv.z + a2.x * gm[0] + a2.y * gm[1] + a2.z * gm[2] + a2.w * gm[3];
      float qm3 = btv.w + a3.x * gm[0] + a3.y * gm[1] + a3.z * gm[2] + a3.w * gm[3];

      float St00 = s0.x * s0.x;
      float St10 = s1.x * s0.x;
      float St11 = s1.x * s1.x + s1.y * s1.y;
      float St20 = s2.x * s0.x;
      float St21 = s2.x * s1.x + s2.y * s1.y;
      float St22 = s2.x * s2.x + s2.y * s2.y + s2.z * s2.z;
      float St30 = s3.x * s0.x;
      float St31 = s3.x * s1.x + s3.y * s1.y;
      float St32 = s3.x * s2.x + s3.y * s2.y + s3.z * s2.z;
      float St33 = s3.x * s3.x + s3.y * s3.y + s3.z * s3.z + s3.w * s3.w;

      float w0x = a0.x * gv[0], w0y = a0.y * gv[1], w0z = a0.z * gv[2], w0w = a0.w * gv[3];
      float w1x = a1.x * gv[0], w1y = a1.y * gv[1], w1z = a1.z * gv[2], w1w = a1.w * gv[3];
      float w2x = a2.x * gv[0], w2y = a2.y * gv[1], w2z = a2.z * gv[2], w2w = a2.w * gv[3];
      float w3x = a3.x * gv[0], w3y = a3.y * gv[1], w3z = a3.z * gv[2], w3w = a3.w * gv[3];
      float qc00 = St00 + w0x * a0.x + w0y * a0.y + w0z * a0.z + w0w * a0.w;
      float qc10 = St10 + w1x * a0.x + w1y * a0.y + w1z * a0.z + w1w * a0.w;
      float qc11 = St11 + w1x * a1.x + w1y * a1.y + w1z * a1.z + w1w * a1.w;
      float qc20 = St20 + w2x * a0.x + w2y * a0.y + w2z * a0.z + w2w * a0.w;
      float qc21 = St21 + w2x * a1.x + w2y * a1.y + w2z * a1.z + w2w * a1.w;
      float qc22 = St22 + w2x * a2.x + w2y * a2.y + w2z * a2.z + w2w * a2.w;
      float qc30 = St30 + w3x * a0.x + w3y * a0.y + w3z * a0.z + w3w * a0.w;
      float qc31 = St31 + w3x * a1.x + w3y * a1.y + w3z * a1.z + w3w * a1.w;
      float qc32 = St32 + w3x * a2.x + w3y * a2.y + w3z * a2.z + w3w * a2.w;
      float qc33 = St33 + w3x * a3.x + w3y * a3.y + w3z * a3.z + w3w * a3.w;

      // Cholesky via rsq (l = t*rsq(t), inv = rsq(t))
      float t00 = qc00 + 1e-6f;
      float i0 = __builtin_amdgcn_rsqf(t00);
      float l00 = t00 * i0;
      float l10 = qc10 * i0, l20 = qc20 * i0, l30 = qc30 * i0;
      float t11 = qc11 + 1e-6f - l10 * l10;
      float i1 = __builtin_amdgcn_rsqf(t11);
      float l11 = t11 * i1;
      float l21 = (qc21 - l20 * l10) * i1;
      float l31 = (qc31 - l30 * l10) * i1;
      float t22 = qc22 + 1e-6f - l20 * l20 - l21 * l21;
      float i2 = __builtin_amdgcn_rsqf(t22);
      float l22 = t22 * i2;
      float l32 = (qc32 - l30 * l20 - l31 * l21) * i2;
      float t33 = qc33 + 1e-6f - l30 * l30 - l31 * l31 - l32 * l32;
      float l33 = t33 * __builtin_amdgcn_rsqf(t33);
      float logdet_q = __logf(t00 * t11 * t22 * t33);

      float dp0 = gv[0] + np_[0], dp1 = gv[1] + np_[1];
      float dp2 = gv[2] + np_[2], dp3 = gv[3] + np_[3];
      float rp0 = __builtin_amdgcn_rcpf(dp0), rp1 = __builtin_amdgcn_rcpf(dp1);
      float rp2 = __builtin_amdgcn_rcpf(dp2), rp3 = __builtin_amdgcn_rcpf(dp3);
      float e0 = gm[0] - qm0, e1 = gm[1] - qm1, e2 = gm[2] - qm2, e3 = gm[3] - qm3;
      float klsum = (qc00 + e0 * e0) * rp0 + (qc11 + e1 * e1) * rp1 +
                    (qc22 + e2 * e2) * rp2 + (qc33 + e3 * e3) * rp3;
      float kl = 0.5f * (klsum - 4.0f + __logf(dp0 * dp1 * dp2 * dp3) - logdet_q);
      kl_acc += kl;

      float dy0 = ov.x - qm0, dy1 = ov.y - qm1, dy2 = ov.z - qm2;
      float es = -0.5f * (cst + (dy0 * dy0 + qc00) * ine0 +
                          (dy1 * dy1 + qc11) * ine1 + (dy2 * dy2 + qc22) * ine2);
      ell_acc += es;

      x0r = qm0 + l00 * ev.x;
      x1r = qm1 + l10 * ev.x + l11 * ev.y;
      x2r = qm2 + l20 * ev.x + l21 * ev.y + l22 * ev.z;
      x3r = qm3 + l30 * ev.x + l31 * ev.y + l32 * ev.z + l33 * ev.w;
    }
  }

  if (m == 0) {
    atomicAdd(&acc[2], kl_acc);
    atomicAdd(&acc[3], ell_acc);
  }
}

// ---------------------------------------------------------------------------
__global__ void finalize_kernel(const float* __restrict__ acc, float* __restrict__ out) {
  if (threadIdx.x == 0 && blockIdx.x == 0) {
    float qm0 = acc[0] / 256.0f;
    float gpKL = acc[1];
    float KL = acc[2] / 4096.0f;
    float lik = acc[3] / 4096.0f;
    float e = -qm0 - gpKL + lik - KL;
    if (lik > KL) e = -qm0 - gpKL + lik / 128.0f - KL;
    out[0] = e;
  }
}

// ---------------------------------------------------------------------------
extern "C" void kernel_launch(void* const* d_in, const int* in_sizes, int n_in,
                              void* d_out, int out_size, void* d_ws, size_t ws_size,
                              hipStream_t stream) {
  const float* obs        = (const float*)d_in[0];
  const float* Z          = (const float*)d_in[1];
  const float* log_ls     = (const float*)d_in[2];
  const float* log_os     = (const float*)d_in[3];
  const float* m_u        = (const float*)d_in[4];
  const float* L_u        = (const float*)d_in[5];
  const float* noise_proc = (const float*)d_in[6];
  const float* noise_emis = (const float*)d_in[7];
  const float* Wih        = (const float*)d_in[8];
  const float* Whh        = (const float*)d_in[9];
  const float* b_lstm     = (const float*)d_in[10];
  const float* Wm         = (const float*)d_in[11];
  const float* bm         = (const float*)d_in[12];
  const float* Wv         = (const float*)d_in[13];
  const float* bv         = (const float*)d_in[14];
  const float* W1         = (const float*)d_in[15];
  const float* b1         = (const float*)d_in[16];
  const float* W2         = (const float*)d_in[17];
  const float* b2         = (const float*)d_in[18];
  const float* W3         = (const float*)d_in[19];
  const float* b3         = (const float*)d_in[20];
  const float* W4         = (const float*)d_in[21];
  const float* b4         = (const float*)d_in[22];

  float* ws = (float*)d_ws;
  float* epsq  = ws;                 // 2097152
  float* m0_g  = epsq + 2097152;     // 1024
  float* v0_g  = m0_g + 1024;        // 1024
  float* par_g = v0_g + 1024;        // 1179648
  float* kinvg = par_g + 1179648;    // 4096
  float* alphg = kinvg + 4096;       // 2048
  float* accp  = alphg + 2048;       // 16

  hipMemsetAsync(accp, 0, 64, stream);

  // JAX: rng = key(42) -> (0,42); k0,kU,kq = split(rng,3)
  uint32_t A0, B0, A1, B1, A2, B2;
  threefry2x32(0u, 42u, 0u, 3u, &A0, &B0);
  threefry2x32(0u, 42u, 1u, 4u, &A1, &B1);
  threefry2x32(0u, 42u, 2u, 5u, &A2, &B2);
  const uint32_t k0a = A0, k0b = A1;   // k0
  const uint32_t kUa = A2, kUb = B0;   // kU
  const uint32_t kqa = B1, kqb = B2;   // kq

  // prep: mlp [0,512) + lstm [512,768) + setup [768,772) + epsq rng [772,4868)
  prep_kernel<<<4868, 256, 0, stream>>>(
      obs, W1, b1, W2, b2, W3, b3, W4, b4,
      Wih, Whh, b_lstm, Wm, bm, Wv, bv,
      Z, log_ls, log_os, m_u, L_u,
      kUa, kUb, kqa, kqb,
      par_g, m0_g, v0_g, kinvg, alphg, epsq, accp);

  scan_kernel<<<512, 256, 0, stream>>>(
      Z, log_ls, log_os, noise_proc, noise_emis, obs,
      par_g, m0_g, v0_g, epsq, kinvg, alphg, k0a, k0b, accp);

  finalize_kernel<<<1, 64, 0, stream>>>(accp, (float*)d_out);
}

// Round 4
// 720.699 us; speedup vs baseline: 1.1037x; 1.1037x over previous
//
#include <hip/hip_runtime.h>
#include <cstdint>
#include <math.h>

// Problem constants
#define NMC   16
#define SDIM  4
#define ODIM  3
#define TLEN  128
#define BDIM  256
#define MDIM  32
#define HLDIM 64
#define PARD  36

#define LOG2PI_F 1.8378770664093453f

// ---------------------------------------------------------------------------
// threefry2x32 (JAX-compatible, 20 rounds)
// ---------------------------------------------------------------------------
__host__ __device__ inline void threefry2x32(uint32_t k0, uint32_t k1,
                                             uint32_t x0, uint32_t x1,
                                             uint32_t* o0, uint32_t* o1) {
  uint32_t ks0 = k0, ks1 = k1, ks2 = k0 ^ k1 ^ 0x1BD11BDAu;
  x0 += ks0; x1 += ks1;
#define TF_R(r) { x0 += x1; x1 = (x1 << (r)) | (x1 >> (32 - (r))); x1 ^= x0; }
  TF_R(13) TF_R(15) TF_R(26) TF_R(6)  x0 += ks1; x1 += ks2 + 1u;
  TF_R(17) TF_R(29) TF_R(16) TF_R(24) x0 += ks2; x1 += ks0 + 2u;
  TF_R(13) TF_R(15) TF_R(26) TF_R(6)  x0 += ks0; x1 += ks1 + 3u;
  TF_R(17) TF_R(29) TF_R(16) TF_R(24) x0 += ks1; x1 += ks2 + 4u;
  TF_R(13) TF_R(15) TF_R(26) TF_R(6)  x0 += ks2; x1 += ks0 + 5u;
#undef TF_R
  *o0 = x0; *o1 = x1;
}

// XLA f32 ErfInv polynomial
__device__ inline float erfinv_f32(float x) {
  float w = -log1pf(-x * x);
  float p;
  if (w < 5.0f) {
    w -= 2.5f;
    p = 2.81022636e-08f;
    p = fmaf(p, w, 3.43273939e-07f);
    p = fmaf(p, w, -3.5233877e-06f);
    p = fmaf(p, w, -4.39150654e-06f);
    p = fmaf(p, w, 0.00021858087f);
    p = fmaf(p, w, -0.00125372503f);
    p = fmaf(p, w, -0.00417768164f);
    p = fmaf(p, w, 0.246640727f);
    p = fmaf(p, w, 1.50140941f);
  } else {
    w = sqrtf(w) - 3.0f;
    p = -0.000200214257f;
    p = fmaf(p, w, 0.000100950558f);
    p = fmaf(p, w, 0.00134934322f);
    p = fmaf(p, w, -0.00367342844f);
    p = fmaf(p, w, 0.00573950773f);
    p = fmaf(p, w, -0.0076224613f);
    p = fmaf(p, w, 0.00943887047f);
    p = fmaf(p, w, 1.00167406f);
    p = fmaf(p, w, 2.83297682f);
  }
  return p * x;
}

__device__ inline float bits_to_normal(uint32_t b) {
  float f = __uint_as_float((b >> 9) | 0x3F800000u) - 1.0f;  // [0,1)
  const float lo = -0.99999994f;
  float u = f * 2.0f + lo;
  u = fmaxf(lo, u);
  return 1.41421356f * erfinv_f32(u);
}

// ---------------------------------------------------------------------------
// DPP-based allreduce over 32 lanes
// ---------------------------------------------------------------------------
#define DPP_ROR_ADD(v, ctrl) \
  ((v) + __int_as_float(__builtin_amdgcn_update_dpp(0, __float_as_int(v), (ctrl), 0xf, 0xf, false)))

__device__ __forceinline__ float allred32(float v) {
  v = DPP_ROR_ADD(v, 0x128);  // row_ror:8
  v = DPP_ROR_ADD(v, 0x124);  // row_ror:4
  v = DPP_ROR_ADD(v, 0x122);  // row_ror:2
  v = DPP_ROR_ADD(v, 0x121);  // row_ror:1
  return v + __shfl_xor(v, 16);
}

__device__ __forceinline__ float sigm_fast(float x) {
  return 1.0f / (1.0f + __expf(-x));
}
__device__ __forceinline__ float tanh_fast(float x) {
  return 1.0f - 2.0f / (1.0f + __expf(2.0f * x));
}

// ===========================================================================
// PREP parts (fused kernel; 256 threads; shared smem arena 12480 floats)
// ===========================================================================

// ---- MLP part: blocks [0,512), 64 rows/block -------------------------------
#define MLP_SB 128
__device__ void mlp_part(
    float* smem, const float* __restrict__ obs,
    const float* __restrict__ W1, const float* __restrict__ b1,
    const float* __restrict__ W2, const float* __restrict__ b2,
    const float* __restrict__ W3, const float* __restrict__ b3,
    const float* __restrict__ W4, const float* __restrict__ b4,
    float* __restrict__ par_g) {
  float* xs  = smem;           // [3][64]
  float* A_l = smem + 192;     // 64*64
  float* B_l = smem + 192 + 4096;  // 64*128
  const int tid = threadIdx.x;
  const int R0 = blockIdx.x * 64;
  const int tr = tid & 15;
  const int tj = tid >> 4;

  for (int idx = tid; idx < 192; idx += 256) {
    int r = idx & 63, o = idx >> 6;
    xs[o * 64 + r] = obs[(R0 + r) * 3 + o];
  }

  float acc2[4][8];
#pragma unroll
  for (int i = 0; i < 4; ++i)
#pragma unroll
    for (int j = 0; j < 8; ++j) acc2[i][j] = 0.f;

  for (int kc = 0; kc < 4; ++kc) {
    __syncthreads();
    {  // stage W2 chunk transposed
      int j = tid & 127, kh = (tid >> 7) * 32;
      const float4* wsrc = (const float4*)(W2 + j * 256 + kc * 64 + kh);
#pragma unroll
      for (int q = 0; q < 8; ++q) {
        float4 v = wsrc[q];
        int k = kh + q * 4;
        B_l[(k + 0) * MLP_SB + j] = v.x;
        B_l[(k + 1) * MLP_SB + j] = v.y;
        B_l[(k + 2) * MLP_SB + j] = v.z;
        B_l[(k + 3) * MLP_SB + j] = v.w;
      }
    }
    {  // layer1 on the fly
      int r = tid & 63, q4 = tid >> 6;
      float x0 = xs[r], x1 = xs[64 + r], x2 = xs[128 + r];
      const float4* w1p = (const float4*)(W1 + (kc * 64 + q4 * 16) * 3);
      float4 wv[12];
#pragma unroll
      for (int q = 0; q < 12; ++q) wv[q] = w1p[q];
      const float* wf = (const float*)wv;
#pragma unroll
      for (int i = 0; i < 16; ++i) {
        int k = q4 * 16 + i;
        float v = b1[kc * 64 + k] + wf[i * 3] * x0 + wf[i * 3 + 1] * x1 + wf[i * 3 + 2] * x2;
        A_l[k * 64 + r] = fmaxf(v, 0.f);
      }
    }
    __syncthreads();
    for (int k = 0; k < 64; ++k) {
      float4 av = *(const float4*)&A_l[k * 64 + tr * 4];
      float4 b0 = *(const float4*)&B_l[k * MLP_SB + tj * 8];
      float4 b1v = *(const float4*)&B_l[k * MLP_SB + tj * 8 + 4];
      const float a4[4] = {av.x, av.y, av.z, av.w};
      const float bv8[8] = {b0.x, b0.y, b0.z, b0.w, b1v.x, b1v.y, b1v.z, b1v.w};
#pragma unroll
      for (int ri = 0; ri < 4; ++ri)
#pragma unroll
        for (int ji = 0; ji < 8; ++ji)
          acc2[ri][ji] = fmaf(a4[ri], bv8[ji], acc2[ri][ji]);
    }
  }
  __syncthreads();
#pragma unroll
  for (int ji = 0; ji < 8; ++ji) {
    int j = tj * 8 + ji;
    float bias = b2[j];
    float4 hv;
    hv.x = fmaxf(acc2[0][ji] + bias, 0.f);
    hv.y = fmaxf(acc2[1][ji] + bias, 0.f);
    hv.z = fmaxf(acc2[2][ji] + bias, 0.f);
    hv.w = fmaxf(acc2[3][ji] + bias, 0.f);
    *(float4*)&B_l[j * 64 + tr * 4] = hv;
  }

  float acc3[4][4];
#pragma unroll
  for (int i = 0; i < 4; ++i)
#pragma unroll
    for (int j = 0; j < 4; ++j) acc3[i][j] = 0.f;

  for (int kc = 0; kc < 2; ++kc) {
    __syncthreads();
    {
      int j = tid & 63, kq = (tid >> 6) * 16;
      const float4* wsrc = (const float4*)(W3 + j * 128 + kc * 64 + kq);
#pragma unroll
      for (int q = 0; q < 4; ++q) {
        float4 v = wsrc[q];
        int k = kq + q * 4;
        A_l[(k + 0) * 64 + j] = v.x;
        A_l[(k + 1) * 64 + j] = v.y;
        A_l[(k + 2) * 64 + j] = v.z;
        A_l[(k + 3) * 64 + j] = v.w;
      }
    }
    __syncthreads();
    for (int k = 0; k < 64; ++k) {
      float4 av = *(const float4*)&B_l[(kc * 64 + k) * 64 + tr * 4];
      float4 bv = *(const float4*)&A_l[k * 64 + (tj & 15) * 4];
      const float a4[4] = {av.x, av.y, av.z, av.w};
      const float b4v[4] = {bv.x, bv.y, bv.z, bv.w};
#pragma unroll
      for (int ri = 0; ri < 4; ++ri)
#pragma unroll
        for (int ji = 0; ji < 4; ++ji)
          acc3[ri][ji] = fmaf(a4[ri], b4v[ji], acc3[ri][ji]);
    }
  }
  __syncthreads();
#pragma unroll
  for (int ji = 0; ji < 4; ++ji) {
    int j = tj * 4 + ji;
    float bias = b3[j];
    float4 hv;
    hv.x = fmaxf(acc3[0][ji] + bias, 0.f);
    hv.y = fmaxf(acc3[1][ji] + bias, 0.f);
    hv.z = fmaxf(acc3[2][ji] + bias, 0.f);
    hv.w = fmaxf(acc3[3][ji] + bias, 0.f);
    *(float4*)&A_l[j * 64 + tr * 4] = hv;
  }
  __syncthreads();

  {
    int r = tid & 63;
    int jg = __builtin_amdgcn_readfirstlane(tid >> 6);
    float accp[9];
#pragma unroll
    for (int i = 0; i < 9; ++i) accp[i] = b4[jg * 9 + i];
    for (int k = 0; k < 64; ++k) {
      float hv = A_l[k * 64 + r];
#pragma unroll
      for (int i = 0; i < 9; ++i)
        accp[i] = fmaf(hv, W4[(jg * 9 + i) * 64 + k], accp[i]);
    }
#pragma unroll
    for (int i = 0; i < 9; ++i) par_g[(R0 + r) * 36 + jg * 9 + i] = accp[i];
  }
}

// ---- LSTM part: blocks [512,768) -------------------------------------------
__device__ void lstm_part(
    float* smem, int b, const float* __restrict__ obs,
    const float* __restrict__ Wih, const float* __restrict__ Whh,
    const float* __restrict__ b_lstm,
    const float* __restrict__ Wm, const float* __restrict__ bm,
    const float* __restrict__ Wv, const float* __restrict__ bv,
    float* __restrict__ m0_g, float* __restrict__ v0_g, float* __restrict__ acc) {
  float* g_l = smem;          // [2][4][64]
  float* h_w = smem + 512;    // [4][64]
  float* mv_l = smem + 768;   // 8
  float* obl = smem + 776;    // [128][4] padded, 16B-aligned
  const int tid = threadIdx.x;
  const int w = tid >> 6;
  const int l = tid & 63;

  for (int i = tid; i < 384; i += 256) obl[(i / 3) * 4 + (i % 3)] = obs[b * 384 + i];

  float whh_r[64];
  {
    const float4* wsrc = (const float4*)(Whh + tid * 64);
#pragma unroll
    for (int q = 0; q < 16; ++q) {
      float4 v = wsrc[q];
      whh_r[q * 4 + 0] = v.x; whh_r[q * 4 + 1] = v.y;
      whh_r[q * 4 + 2] = v.z; whh_r[q * 4 + 3] = v.w;
    }
  }
  const float wih0 = Wih[tid * 3 + 0];
  const float wih1 = Wih[tid * 3 + 1];
  const float wih2 = Wih[tid * 3 + 2];
  const float bb = b_lstm[tid];

  float c_ = 0.0f;
  h_w[w * 64 + l] = 0.0f;
  __syncthreads();

#pragma unroll 1
  for (int t = 0; t < TLEN; ++t) {
    const float4 xv = *(const float4*)&obl[t * 4];
    const float4* h4 = (const float4*)&h_w[w * 64];
    float a0 = 0.f, a1 = 0.f, a2 = 0.f, a3 = 0.f;
#pragma unroll
    for (int q = 0; q < 16; ++q) {
      float4 hv = h4[q];
      a0 = fmaf(whh_r[q * 4 + 0], hv.x, a0);
      a1 = fmaf(whh_r[q * 4 + 1], hv.y, a1);
      a2 = fmaf(whh_r[q * 4 + 2], hv.z, a2);
      a3 = fmaf(whh_r[q * 4 + 3], hv.w, a3);
    }
    float g = fmaf(wih0, xv.x, fmaf(wih1, xv.y, fmaf(wih2, xv.z, bb))) + ((a0 + a1) + (a2 + a3));
    g_l[((t & 1) * 4 + w) * 64 + l] = g;
    __syncthreads();
    float gi = g_l[((t & 1) * 4 + 0) * 64 + l];
    float gf = g_l[((t & 1) * 4 + 1) * 64 + l];
    float gg = g_l[((t & 1) * 4 + 2) * 64 + l];
    float go = g_l[((t & 1) * 4 + 3) * 64 + l];
    c_ = sigm_fast(gf) * c_ + sigm_fast(gi) * tanh_fast(gg);
    h_w[w * 64 + l] = sigm_fast(go) * tanh_fast(c_);
  }

  if (tid < 8) {
    const int s = tid & 3;
    const bool isv = tid >= 4;
    const float* W = isv ? (Wv + s * 64) : (Wm + s * 64);
    float a = isv ? bv[s] : bm[s];
#pragma unroll
    for (int k = 0; k < 64; ++k) a += W[k] * h_w[k];
    if (!isv) {
      m0_g[b * 4 + s] = a;
      mv_l[s] = a;
    } else {
      float sp = (a > 0.f) ? (a + log1pf(expf(-a))) : log1pf(expf(a));
      float v = sp + 1e-6f;
      v0_g[b * 4 + s] = v;
      mv_l[4 + s] = v;
    }
  }
  if (tid == 0) {
    float s = 0.f;
#pragma unroll
    for (int k = 0; k < 4; ++k) {
      float m = mv_l[k], v = mv_l[4 + k];
      s += 0.5f * (v + m * m - 1.0f - logf(v));
    }
    atomicAdd(&acc[0], s);
  }
}

// ---- SETUP part: blocks [768,772), per-d -----------------------------------
__device__ void setup_part(
    float* smem, int d, const float* __restrict__ Z,
    const float* __restrict__ log_ls, const float* __restrict__ log_os,
    const float* __restrict__ m_u, const float* __restrict__ L_u,
    uint32_t kUa, uint32_t kUb,
    float* __restrict__ Kinv_g, float* __restrict__ alpha_g, float* __restrict__ acc) {
  float* Kl    = smem;          // 32*33
  float* work  = smem + 1056;   // 32*33
  float* Ul    = smem + 2112;   // 16*32
  float* red   = smem + 2624;   // 64
  float* epsUl = smem + 2688;   // 16*32
  const int tid = threadIdx.x;

  {
    int nn7 = tid >> 5, k = tid & 31;
    uint32_t j = (uint32_t)((nn7 * 4 + d) * 32 + k);
    uint32_t o0, o1;
    threefry2x32(kUa, kUb, j, j + 1024u, &o0, &o1);
    epsUl[nn7 * 32 + k] = bits_to_normal(o0);
    epsUl[(nn7 + 8) * 32 + k] = bits_to_normal(o1);
  }

  float il[4];
#pragma unroll
  for (int k = 0; k < 4; ++k) il[k] = expf(-log_ls[d * 4 + k]);
  const float osd = expf(log_os[d]);

  for (int e = tid; e < 1024; e += 256) {
    int i = e >> 5, j = e & 31;
    float s = 0.f;
#pragma unroll
    for (int k = 0; k < 4; ++k) {
      float t_ = (Z[d * 128 + i * 4 + k] - Z[d * 128 + j * 4 + k]) * il[k];
      s += t_ * t_;
    }
    float v = osd * expf(-0.5f * s);
    if (i == j) v += 1e-5f;
    Kl[i * 33 + j] = v;
  }
  __syncthreads();

  for (int jc = 0; jc < 32; ++jc) {
    if (tid == jc) {
      float s = Kl[jc * 33 + jc];
      for (int p = 0; p < jc; ++p) s -= Kl[jc * 33 + p] * Kl[jc * 33 + p];
      Kl[jc * 33 + jc] = sqrtf(s);
    }
    __syncthreads();
    if (tid > jc && tid < 32) {
      float s = Kl[tid * 33 + jc];
      for (int p = 0; p < jc; ++p) s -= Kl[tid * 33 + p] * Kl[jc * 33 + p];
      Kl[tid * 33 + jc] = s / Kl[jc * 33 + jc];
    }
    __syncthreads();
  }

  if (tid < 32) {
    const int col = tid;
    float rdiag[32];
#pragma unroll
    for (int r = 0; r < 32; ++r) rdiag[r] = __builtin_amdgcn_rcpf(Kl[r * 33 + r]);
    float w[32];
#pragma unroll
    for (int r = 0; r < 32; ++r) {
      float s = (r == col) ? 1.f : 0.f;
#pragma unroll
      for (int p = 0; p < 32; ++p)
        if (p < r) s -= Kl[r * 33 + p] * w[p];
      w[r] = s * rdiag[r];
    }
    float w2[32];
#pragma unroll
    for (int rr = 0; rr < 32; ++rr) {
      const int r = 31 - rr;
      float s = w[r];
#pragma unroll
      for (int p = 0; p < 32; ++p)
        if (p > r) s -= Kl[p * 33 + r] * w2[p];
      w2[r] = s * rdiag[r];
    }
#pragma unroll
    for (int r = 0; r < 32; ++r) {
      Kinv_g[(d * 32 + r) * 32 + col] = w2[r];
      work[col * 33 + r] = w2[r];
    }
  }
  for (int e = tid; e < 512; e += 256) {
    int nn = e >> 5, m = e & 31;
    float s = m_u[d * 32 + m];
    for (int k = 0; k <= m; ++k)
      s += L_u[(d * 32 + m) * 32 + k] * epsUl[nn * 32 + k];
    Ul[nn * 32 + m] = s;
  }
  __syncthreads();
  for (int e = tid; e < 512; e += 256) {
    int nn = e >> 5, m = e & 31;
    float s = 0.f;
    for (int mm = 0; mm < 32; ++mm) s += work[mm * 33 + m] * Ul[nn * 32 + mm];
    alpha_g[(d * 16 + nn) * 32 + m] = s;
  }

  float contrib = 0.f;
  if (tid < 32) {
    const int col = tid;
    float rdiag[32];
#pragma unroll
    for (int r = 0; r < 32; ++r) rdiag[r] = __builtin_amdgcn_rcpf(Kl[r * 33 + r]);
    float v[32];
    float sa = 0.f;
#pragma unroll
    for (int r = 0; r < 32; ++r) {
      float lu = L_u[(d * 32 + r) * 32 + col];
      float s = (col <= r) ? lu : 0.f;
#pragma unroll
      for (int p = 0; p < 32; ++p)
        if (p < r) s -= Kl[r * 33 + p] * v[p];
      float vv = s * rdiag[r];
      v[r] = vv;
      sa += vv * vv;
    }
    contrib = sa;
  } else if (tid < 64) {
    float bq[32];
    float sb = 0.f;
#pragma unroll
    for (int r = 0; r < 32; ++r) {
      float s = m_u[d * 32 + r];
#pragma unroll
      for (int p = 0; p < 32; ++p)
        if (p < r) s -= Kl[r * 33 + p] * bq[p];
      float vv = s * __builtin_amdgcn_rcpf(Kl[r * 33 + r]);
      bq[r] = vv;
      sb += vv * vv;
    }
    contrib = (tid == 32) ? sb : 0.f;
  }
  if (tid < 64) red[tid] = contrib;
  __syncthreads();
  if (tid == 0) {
    float s = 0.f;
    for (int i = 0; i < 64; ++i) s += red[i];
    float ldK = 0.f, ldS = 0.f;
    for (int r = 0; r < 32; ++r) {
      ldK += logf(Kl[r * 33 + r]);
      ldS += logf(fabsf(L_u[(d * 32 + r) * 32 + r]) + 1e-12f);
    }
    float g = s - 32.0f + 2.0f * ldK - 2.0f * ldS;
    atomicAdd(&acc[1], 0.5f * g / (128.0f * 256.0f));
  }
}

// ---- Fused prep kernel (772 blocks) ----------------------------------------
__global__ __launch_bounds__(256) void prep_kernel(
    const float* obs,
    const float* W1, const float* b1, const float* W2, const float* b2,
    const float* W3, const float* b3, const float* W4, const float* b4,
    const float* Wih, const float* Whh, const float* b_lstm,
    const float* Wm, const float* bm, const float* Wv, const float* bv,
    const float* Z, const float* log_ls, const float* log_os,
    const float* m_u, const float* L_u,
    uint32_t kUa, uint32_t kUb,
    float* par_g, float* m0_g, float* v0_g,
    float* Kinv_g, float* alpha_g, float* acc) {
  __shared__ __align__(16) float smem[12480];
  const int bx = blockIdx.x;
  if (bx < 512) {
    mlp_part(smem, obs, W1, b1, W2, b2, W3, b3, W4, b4, par_g);
  } else if (bx < 768) {
    lstm_part(smem, bx - 512, obs, Wih, Whh, b_lstm, Wm, bm, Wv, bv, m0_g, v0_g, acc);
  } else {
    setup_part(smem, bx - 768, Z, log_ls, log_os, m_u, L_u, kUa, kUb,
               Kinv_g, alpha_g, acc);
  }
}

// ===========================================================================
// Scan: 4096 chains; 32 lanes/chain; all RNG generated in-block into LDS
// (threefry pair (j, j+2^20) == (t, t+64) for same (n,b,s) -> block-local).
// ===========================================================================
__global__ __launch_bounds__(256)
__attribute__((amdgpu_waves_per_eu(2, 2)))
void scan_kernel(
    const float* __restrict__ Z, const float* __restrict__ log_ls,
    const float* __restrict__ log_os, const float* __restrict__ noise_proc,
    const float* __restrict__ noise_emis, const float* __restrict__ obs,
    const float* __restrict__ par_g, const float* __restrict__ m0_g,
    const float* __restrict__ v0_g,
    const float* __restrict__ Kinv_g, const float* __restrict__ alpha_g,
    uint32_t k0a, uint32_t k0b, uint32_t kqa, uint32_t kqb,
    float* __restrict__ acc) {
  __shared__ __align__(16) float parl[32 * 36];
  __shared__ __align__(16) float obsl[32 * 4];
  __shared__ __align__(16) float eps0l[8 * 4 * 4];
  __shared__ __align__(16) float kbuf[8 * 4 * 32];
  __shared__ __align__(16) float epsl[128 * 8 * 4];  // [t][c][s], 16 KB
  const int tid = threadIdx.x;
  const int c = tid >> 5;
  const int m = tid & 31;
  const int b = blockIdx.x >> 1;
  const int nb = (blockIdx.x & 1) << 3;
  const int n = nb + c;

  // --- prologue RNG ---
  // eps0: pairs (j, j+32768) -> n and n+8
  if (tid < 128) {
    int cc = tid >> 4, dd = (tid >> 2) & 3, ss = tid & 3;
    uint32_t j = (uint32_t)((((cc * 4 + dd) * 256 + b) * 4) + ss);
    uint32_t o0, o1;
    threefry2x32(k0a, k0b, j, j + 32768u, &o0, &o1);
    eps0l[(cc * 4 + dd) * 4 + ss] = bits_to_normal(nb ? o1 : o0);
  }
  // eps_q: this block's slice. e = t*32 + c*4 + s for t in [0,64);
  // o0 -> step t, o1 -> step t+64 (j + 2^20 == t+64 same n,b,s).
#pragma unroll
  for (int i = 0; i < 8; ++i) {
    int e = tid + 256 * i;
    int t = e >> 5, cc = (e >> 2) & 7, ss = e & 3;
    uint32_t j = (uint32_t)(((t * 16 + nb + cc) * 256 + b) * 4 + ss);
    uint32_t o0, o1;
    threefry2x32(kqa, kqb, j, j + 1048576u, &o0, &o1);
    epsl[e] = bits_to_normal(o0);               // (t*8+cc)*4+ss == e
    epsl[((t + 64) * 8 + cc) * 4 + ss] = bits_to_normal(o1);
  }

  float zr[4][4], ilr[4][4], osr[4];
#pragma unroll
  for (int d = 0; d < 4; ++d) {
#pragma unroll
    for (int k = 0; k < 4; ++k) {
      zr[d][k] = Z[d * 128 + m * 4 + k];
      ilr[d][k] = expf(-log_ls[d * 4 + k]);
    }
    osr[d] = expf(log_os[d]);
  }
  float kinv[4][32];
  {
    const float4* kg4 = (const float4*)Kinv_g;
#pragma unroll
    for (int d = 0; d < 4; ++d) {
#pragma unroll
      for (int q = 0; q < 8; ++q) {
        float4 v = kg4[(d * 32 + m) * 8 + q];
        kinv[d][q * 4 + 0] = v.x;
        kinv[d][q * 4 + 1] = v.y;
        kinv[d][q * 4 + 2] = v.z;
        kinv[d][q * 4 + 3] = v.w;
      }
    }
  }
  float alr[4];
#pragma unroll
  for (int d = 0; d < 4; ++d) alr[d] = alpha_g[(d * 16 + n) * 32 + m];
  float np_[4];
#pragma unroll
  for (int k = 0; k < 4; ++k) np_[k] = noise_proc[k];
  const float ine0 = __builtin_amdgcn_rcpf(noise_emis[0]);
  const float ine1 = __builtin_amdgcn_rcpf(noise_emis[1]);
  const float ine2 = __builtin_amdgcn_rcpf(noise_emis[2]);
  const float cst = 3.0f * LOG2PI_F + logf(noise_emis[0]) + logf(noise_emis[1]) + logf(noise_emis[2]);

  const float4 m0v = *(const float4*)(m0_g + b * 4);
  const float4 v0v = *(const float4*)(v0_g + b * 4);
  const float sq0 = sqrtf(v0v.x), sq1 = sqrtf(v0v.y), sq2 = sqrtf(v0v.z), sq3 = sqrtf(v0v.w);

  float x0r = 0.f, x1r = 0.f, x2r = 0.f, x3r = 0.f;
  float kl_acc = 0.f, ell_acc = 0.f;

  for (int tc = 0; tc < 4; ++tc) {
    __syncthreads();
    {  // stage par chunk (32 steps x 36) and obs chunk
      const float4* src = (const float4*)(par_g + (size_t)b * 4608 + tc * 1152);
      float4* dst = (float4*)parl;
      for (int i = tid; i < 288; i += 256) dst[i] = src[i];
      if (tid < 96) obsl[(tid / 3) * 4 + (tid % 3)] = obs[b * 384 + tc * 96 + tid];
    }
    __syncthreads();

#pragma unroll 1
    for (int tt = 0; tt < 32; ++tt) {
      const int t = tc * 32 + tt;
      const float4* pv = (const float4*)&parl[tt * 36];
      const float4 a0 = pv[0], a1 = pv[1], a2 = pv[2], a3 = pv[3];
      const float4 btv = pv[4];
      const float4 s0 = pv[5], s1 = pv[6], s2 = pv[7], s3 = pv[8];
      const float4 ov = *(const float4*)&obsl[tt * 4];
      const float4 ev = *(const float4*)&epsl[(t * 8 + c) * 4];

      // phase 1: RBF features
      float kreg[4];
#pragma unroll
      for (int d = 0; d < 4; ++d) {
        float xt0, xt1, xt2, xt3;
        if (t == 0) {
          const float4 e0 = *(const float4*)&eps0l[(c * 4 + d) * 4];
          xt0 = fmaf(sq0, e0.x, m0v.x);
          xt1 = fmaf(sq1, e0.y, m0v.y);
          xt2 = fmaf(sq2, e0.z, m0v.z);
          xt3 = fmaf(sq3, e0.w, m0v.w);
        } else {
          xt0 = x0r; xt1 = x1r; xt2 = x2r; xt3 = x3r;
        }
        float d0_ = (xt0 - zr[d][0]) * ilr[d][0];
        float d1_ = (xt1 - zr[d][1]) * ilr[d][1];
        float d2_ = (xt2 - zr[d][2]) * ilr[d][2];
        float d3_ = (xt3 - zr[d][3]) * ilr[d][3];
        float ss = d0_ * d0_ + d1_ * d1_ + d2_ * d2_ + d3_ * d3_;
        float km = osr[d] * __expf(-0.5f * ss);
        kreg[d] = km;
        kbuf[(c * 4 + d) * 32 + m] = km;  // half-wave private
      }

      // phase 2: mean / quad form
      float gm[4], gv[4];
#pragma unroll
      for (int d = 0; d < 4; ++d) {
        const float4* kb4 = (const float4*)&kbuf[(c * 4 + d) * 32];
        float ya = 0.f, yb = 0.f, yc = 0.f, yd = 0.f;
#pragma unroll
        for (int q = 0; q < 8; ++q) {
          float4 kv = kb4[q];
          ya = fmaf(kinv[d][q * 4 + 0], kv.x, ya);
          yb = fmaf(kinv[d][q * 4 + 1], kv.y, yb);
          yc = fmaf(kinv[d][q * 4 + 2], kv.z, yc);
          yd = fmaf(kinv[d][q * 4 + 3], kv.w, yd);
        }
        float y = (ya + yb) + (yc + yd);
        gm[d] = allred32(kreg[d] * alr[d]);
        float qp = allred32(kreg[d] * y);
        gv[d] = fmaxf(osr[d] - qp, 1e-8f);
      }

      // tail
      float qm0 = btv.x + a0.x * gm[0] + a0.y * gm[1] + a0.z * gm[2] + a0.w * gm[3];
      float qm1 = btv.y + a1.x * gm[0] + a1.y * gm[1] + a1.z * gm[2] + a1.w * gm[3];
      float qm2 = btv.z + a2.x * gm[0] + a2.y * gm[1] + a2.z * gm[2] + a2.w * gm[3];
      float qm3 = btv.w + a3.x * gm[0] + a3.y * gm[1] + a3.z * gm[2] + a3.w * gm[3];

      float St00 = s0.x * s0.x;
      float St10 = s1.x * s0.x;
      float St11 = s1.x * s1.x + s1.y * s1.y;
      float St20 = s2.x * s0.x;
      float St21 = s2.x * s1.x + s2.y * s1.y;
      float St22 = s2.x * s2.x + s2.y * s2.y + s2.z * s2.z;
      float St30 = s3.x * s0.x;
      float St31 = s3.x * s1.x + s3.y * s1.y;
      float St32 = s3.x * s2.x + s3.y * s2.y + s3.z * s2.z;
      float St33 = s3.x * s3.x + s3.y * s3.y + s3.z * s3.z + s3.w * s3.w;

      float w0x = a0.x * gv[0], w0y = a0.y * gv[1], w0z = a0.z * gv[2], w0w = a0.w * gv[3];
      float w1x = a1.x * gv[0], w1y = a1.y * gv[1], w1z = a1.z * gv[2], w1w = a1.w * gv[3];
      float w2x = a2.x * gv[0], w2y = a2.y * gv[1], w2z = a2.z * gv[2], w2w = a2.w * gv[3];
      float w3x = a3.x * gv[0], w3y = a3.y * gv[1], w3z = a3.z * gv[2], w3w = a3.w * gv[3];
      float qc00 = St00 + w0x * a0.x + w0y * a0.y + w0z * a0.z + w0w * a0.w;
      float qc10 = St10 + w1x * a0.x + w1y * a0.y + w1z * a0.z + w1w * a0.w;
      float qc11 = St11 + w1x * a1.x + w1y * a1.y + w1z * a1.z + w1w * a1.w;
      float qc20 = St20 + w2x * a0.x + w2y * a0.y + w2z * a0.z + w2w * a0.w;
      float qc21 = St21 + w2x * a1.x + w2y * a1.y + w2z * a1.z + w2w * a1.w;
      float qc22 = St22 + w2x * a2.x + w2y * a2.y + w2z * a2.z + w2w * a2.w;
      float qc30 = St30 + w3x * a0.x + w3y * a0.y + w3z * a0.z + w3w * a0.w;
      float qc31 = St31 + w3x * a1.x + w3y * a1.y + w3z * a1.z + w3w * a1.w;
      float qc32 = St32 + w3x * a2.x + w3y * a2.y + w3z * a2.z + w3w * a2.w;
      float qc33 = St33 + w3x * a3.x + w3y * a3.y + w3z * a3.z + w3w * a3.w;

      float t00 = qc00 + 1e-6f;
      float i0 = __builtin_amdgcn_rsqf(t00);
      float l00 = t00 * i0;
      float l10 = qc10 * i0, l20 = qc20 * i0, l30 = qc30 * i0;
      float t11 = qc11 + 1e-6f - l10 * l10;
      float i1 = __builtin_amdgcn_rsqf(t11);
      float l11 = t11 * i1;
      float l21 = (qc21 - l20 * l10) * i1;
      float l31 = (qc31 - l30 * l10) * i1;
      float t22 = qc22 + 1e-6f - l20 * l20 - l21 * l21;
      float i2 = __builtin_amdgcn_rsqf(t22);
      float l22 = t22 * i2;
      float l32 = (qc32 - l30 * l20 - l31 * l21) * i2;
      float t33 = qc33 + 1e-6f - l30 * l30 - l31 * l31 - l32 * l32;
      float l33 = t33 * __builtin_amdgcn_rsqf(t33);
      float logdet_q = __logf(t00 * t11 * t22 * t33);

      float dp0 = gv[0] + np_[0], dp1 = gv[1] + np_[1];
      float dp2 = gv[2] + np_[2], dp3 = gv[3] + np_[3];
      float rp0 = __builtin_amdgcn_rcpf(dp0), rp1 = __builtin_amdgcn_rcpf(dp1);
      float rp2 = __builtin_amdgcn_rcpf(dp2), rp3 = __builtin_amdgcn_rcpf(dp3);
      float e0 = gm[0] - qm0, e1 = gm[1] - qm1, e2 = gm[2] - qm2, e3 = gm[3] - qm3;
      float klsum = (qc00 + e0 * e0) * rp0 + (qc11 + e1 * e1) * rp1 +
                    (qc22 + e2 * e2) * rp2 + (qc33 + e3 * e3) * rp3;
      float kl = 0.5f * (klsum - 4.0f + __logf(dp0 * dp1 * dp2 * dp3) - logdet_q);
      kl_acc += kl;

      float dy0 = ov.x - qm0, dy1 = ov.y - qm1, dy2 = ov.z - qm2;
      float es = -0.5f * (cst + (dy0 * dy0 + qc00) * ine0 +
                          (dy1 * dy1 + qc11) * ine1 + (dy2 * dy2 + qc22) * ine2);
      ell_acc += es;

      x0r = qm0 + l00 * ev.x;
      x1r = qm1 + l10 * ev.x + l11 * ev.y;
      x2r = qm2 + l20 * ev.x + l21 * ev.y + l22 * ev.z;
      x3r = qm3 + l30 * ev.x + l31 * ev.y + l32 * ev.z + l33 * ev.w;
    }
  }

  if (m == 0) {
    atomicAdd(&acc[2], kl_acc);
    atomicAdd(&acc[3], ell_acc);
  }
}

// ---------------------------------------------------------------------------
__global__ void finalize_kernel(const float* __restrict__ acc, float* __restrict__ out) {
  if (threadIdx.x == 0 && blockIdx.x == 0) {
    float qm0 = acc[0] / 256.0f;
    float gpKL = acc[1];
    float KL = acc[2] / 4096.0f;
    float lik = acc[3] / 4096.0f;
    float e = -qm0 - gpKL + lik - KL;
    if (lik > KL) e = -qm0 - gpKL + lik / 128.0f - KL;
    out[0] = e;
  }
}

// ---------------------------------------------------------------------------
extern "C" void kernel_launch(void* const* d_in, const int* in_sizes, int n_in,
                              void* d_out, int out_size, void* d_ws, size_t ws_size,
                              hipStream_t stream) {
  const float* obs        = (const float*)d_in[0];
  const float* Z          = (const float*)d_in[1];
  const float* log_ls     = (const float*)d_in[2];
  const float* log_os     = (const float*)d_in[3];
  const float* m_u        = (const float*)d_in[4];
  const float* L_u        = (const float*)d_in[5];
  const float* noise_proc = (const float*)d_in[6];
  const float* noise_emis = (const float*)d_in[7];
  const float* Wih        = (const float*)d_in[8];
  const float* Whh        = (const float*)d_in[9];
  const float* b_lstm     = (const float*)d_in[10];
  const float* Wm         = (const float*)d_in[11];
  const float* bm         = (const float*)d_in[12];
  const float* Wv         = (const float*)d_in[13];
  const float* bv         = (const float*)d_in[14];
  const float* W1         = (const float*)d_in[15];
  const float* b1         = (const float*)d_in[16];
  const float* W2         = (const float*)d_in[17];
  const float* b2         = (const float*)d_in[18];
  const float* W3         = (const float*)d_in[19];
  const float* b3         = (const float*)d_in[20];
  const float* W4         = (const float*)d_in[21];
  const float* b4         = (const float*)d_in[22];

  float* ws = (float*)d_ws;
  float* m0_g  = ws;                 // 1024
  float* v0_g  = m0_g + 1024;        // 1024
  float* par_g = v0_g + 1024;        // 1179648
  float* kinvg = par_g + 1179648;    // 4096
  float* alphg = kinvg + 4096;       // 2048
  float* accp  = alphg + 2048;       // 16

  hipMemsetAsync(accp, 0, 64, stream);

  // JAX: rng = key(42) -> (0,42); k0,kU,kq = split(rng,3)
  uint32_t A0, B0, A1, B1, A2, B2;
  threefry2x32(0u, 42u, 0u, 3u, &A0, &B0);
  threefry2x32(0u, 42u, 1u, 4u, &A1, &B1);
  threefry2x32(0u, 42u, 2u, 5u, &A2, &B2);
  const uint32_t k0a = A0, k0b = A1;   // k0
  const uint32_t kUa = A2, kUb = B0;   // kU
  const uint32_t kqa = B1, kqb = B2;   // kq

  // prep: mlp [0,512) + lstm [512,768) + setup [768,772)
  prep_kernel<<<772, 256, 0, stream>>>(
      obs, W1, b1, W2, b2, W3, b3, W4, b4,
      Wih, Whh, b_lstm, Wm, bm, Wv, bv,
      Z, log_ls, log_os, m_u, L_u,
      kUa, kUb,
      par_g, m0_g, v0_g, kinvg, alphg, accp);

  scan_kernel<<<512, 256, 0, stream>>>(
      Z, log_ls, log_os, noise_proc, noise_emis, obs,
      par_g, m0_g, v0_g, kinvg, alphg, k0a, k0b, kqa, kqb, accp);

  finalize_kernel<<<1, 64, 0, stream>>>(accp, (float*)d_out);
}